// Round 1
// baseline (846.805 us; speedup 1.0000x reference)
//
#include <hip/hip_runtime.h>
#include <hip/hip_bf16.h>
#include <stdint.h>

// ---------------------------------------------------------------------------
// Mamba2 block: x@w_in^T -> split(xi,gate) -> depthwise causal conv4 + silu
//               -> *D*silu(gate) -> @w_out^T
// B=4, T=2048, D_MODEL=2048, D_INNER=4096.  All GEMMs in bf16 MFMA, fp32 acc.
// ---------------------------------------------------------------------------

#define BT_TOTAL 8192   // B*T
#define DM 2048
#define DI 4096

typedef __attribute__((ext_vector_type(8))) short short8;   // 8 x bf16 (4 VGPR)
typedef __attribute__((ext_vector_type(4))) float f32x4;    // MFMA C/D

__device__ __forceinline__ void async_ld16(const void* g, void* l) {
    // global -> LDS direct DMA, 16B per lane. LDS dest is wave-uniform base +
    // lane*16; our chunk indexing (c = wave*64 + lane + t*256) satisfies that.
    __builtin_amdgcn_global_load_lds(
        (__attribute__((address_space(1))) void*)g,
        (__attribute__((address_space(3))) void*)l,
        16, 0, 0);
}

// gemm_bt: C[M,N] = A[M,K] * B[N,K]^T   (both K-contiguous), bf16 in, fp32 acc.
// 128x128 tile, BK=64, 256 threads = 4 waves in 2x2, each wave 64x64 via
// 4x4 grid of 16x16x32 MFMA tiles.  m97-ladder structure (~874 TF @4k^3).
template<bool OUT_BF16>
__global__ __launch_bounds__(256) void gemm_bt_kernel(
    const ushort* __restrict__ A, const ushort* __restrict__ B,
    void* __restrict__ Cp, int M, int N, int K)
{
    __shared__ ushort As[128 * 64];   // 16 KiB
    __shared__ ushort Bs[128 * 64];   // 16 KiB

    const int tid  = threadIdx.x;
    const int lane = tid & 63;
    const int wave = tid >> 6;
    const int wm   = (wave >> 1) * 64;   // wave row offset inside tile
    const int wn   = (wave & 1) * 64;    // wave col offset inside tile
    const int lr   = lane & 15;
    const int quad = lane >> 4;

    const int bm = blockIdx.y * 128;
    const int bn = blockIdx.x * 128;

    f32x4 acc[4][4];
#pragma unroll
    for (int i = 0; i < 4; ++i)
#pragma unroll
        for (int j = 0; j < 4; ++j)
            acc[i][j] = (f32x4){0.f, 0.f, 0.f, 0.f};

    // Staging: each tile is 128 rows x 64 bf16 = 16 KiB = 1024 x 16B chunks.
    // 256 threads x 4 chunks.  chunk c: row = c>>3, k-offset = (c&7)*8 elems.
    const ushort* ag[4];
    const ushort* bg[4];
    ushort* al[4];
    ushort* bl[4];
#pragma unroll
    for (int t = 0; t < 4; ++t) {
        const int c  = tid + t * 256;
        const int r  = c >> 3;
        const int co = (c & 7) * 8;
        ag[t] = A + (size_t)(bm + r) * (size_t)K + co;
        bg[t] = B + (size_t)(bn + r) * (size_t)K + co;
        al[t] = &As[c * 8];
        bl[t] = &Bs[c * 8];
    }

    for (int kk = 0; kk < K; kk += 64) {
        __syncthreads();                 // everyone done reading previous tile
#pragma unroll
        for (int t = 0; t < 4; ++t) {
            async_ld16(ag[t] + kk, al[t]);
            async_ld16(bg[t] + kk, bl[t]);
        }
        __syncthreads();                 // compiler drains vmcnt before barrier

#pragma unroll
        for (int ks = 0; ks < 64; ks += 32) {
            short8 af[4], bfr[4];
#pragma unroll
            for (int mt = 0; mt < 4; ++mt)
                af[mt] = *(const short8*)&As[(wm + mt * 16 + lr) * 64 + ks + quad * 8];
#pragma unroll
            for (int nt = 0; nt < 4; ++nt)
                bfr[nt] = *(const short8*)&Bs[(wn + nt * 16 + lr) * 64 + ks + quad * 8];
#pragma unroll
            for (int mt = 0; mt < 4; ++mt)
#pragma unroll
                for (int nt = 0; nt < 4; ++nt)
                    acc[mt][nt] = __builtin_amdgcn_mfma_f32_16x16x32_bf16(
                        af[mt], bfr[nt], acc[mt][nt], 0, 0, 0);
        }
    }

    // Epilogue. C/D layout (verified m89/m91): col = lane&15, row = quad*4+reg.
    const int row0 = bm + wm + quad * 4;
    const int col0 = bn + wn + lr;
    if (OUT_BF16) {
        __hip_bfloat16* C = (__hip_bfloat16*)Cp;
#pragma unroll
        for (int mt = 0; mt < 4; ++mt)
#pragma unroll
            for (int r = 0; r < 4; ++r) {
                const int gr = row0 + mt * 16 + r;
                __hip_bfloat16* Crow = C + (size_t)gr * (size_t)N + col0;
#pragma unroll
                for (int nt = 0; nt < 4; ++nt)
                    Crow[nt * 16] = __float2bfloat16(acc[mt][nt][r]);
            }
    } else {
        float* C = (float*)Cp;
#pragma unroll
        for (int mt = 0; mt < 4; ++mt)
#pragma unroll
            for (int r = 0; r < 4; ++r) {
                const int gr = row0 + mt * 16 + r;
                float* Crow = C + (size_t)gr * (size_t)N + col0;
#pragma unroll
                for (int nt = 0; nt < 4; ++nt)
                    Crow[nt * 16] = acc[mt][nt][r];
            }
    }
}

// Depthwise causal conv (4 taps) + silu, * D, * silu(gate).
// xp = x_proj bf16 [8192][8192] (first 4096 = xi, last 4096 = gate)
// h  = bf16 [8192][4096]
__global__ __launch_bounds__(256) void conv_silu_kernel(
    const __hip_bfloat16* __restrict__ xp,
    const float* __restrict__ cw,   // [4096][4]
    const float* __restrict__ cb,   // [4096]
    const float* __restrict__ Dv,   // [4096]
    __hip_bfloat16* __restrict__ h)
{
    const int idx = blockIdx.x * 256 + threadIdx.x;   // over 8192*4096
    const int d  = idx & (DI - 1);
    const int bt = idx >> 12;
    const int t  = bt & 2047;

    const float gate = __bfloat162float(xp[(size_t)bt * (2 * DI) + DI + d]);

    float a = cb[d];
    const float4 w = *(const float4*)(cw + d * 4);
    const float wk[4] = {w.x, w.y, w.z, w.w};
#pragma unroll
    for (int k = 0; k < 4; ++k) {
        const int tt = t - 3 + k;
        if (tt >= 0)
            a += __bfloat162float(xp[(size_t)(bt - 3 + k) * (2 * DI) + d]) * wk[k];
    }
    const float sc = a / (1.f + __expf(-a));
    const float sg = gate / (1.f + __expf(-gate));
    h[(size_t)bt * DI + d] = __float2bfloat16(sc * Dv[d] * sg);
}

__global__ __launch_bounds__(256) void f32_to_bf16_x4(
    const float* __restrict__ in, __hip_bfloat16* __restrict__ out, int n4)
{
    const int i = blockIdx.x * 256 + threadIdx.x;
    if (i >= n4) return;
    const float4 v = *(const float4*)(in + (size_t)i * 4);
    union { __hip_bfloat16 hh[4]; ushort4 u; } cv;
    cv.hh[0] = __float2bfloat16(v.x);
    cv.hh[1] = __float2bfloat16(v.y);
    cv.hh[2] = __float2bfloat16(v.z);
    cv.hh[3] = __float2bfloat16(v.w);
    *(ushort4*)((ushort*)out + (size_t)i * 4) = cv.u;
}

extern "C" void kernel_launch(void* const* d_in, const int* in_sizes, int n_in,
                              void* d_out, int out_size, void* d_ws, size_t ws_size,
                              hipStream_t stream)
{
    const float* x     = (const float*)d_in[0];   // [4,2048,2048]
    const float* w_in  = (const float*)d_in[1];   // [8192,2048]
    const float* w_out = (const float*)d_in[2];   // [2048,4096]
    const float* cw    = (const float*)d_in[3];   // [4096,1,4]
    const float* cb    = (const float*)d_in[4];   // [4096]
    const float* Dv    = (const float*)d_in[5];   // [4096]
    float* out = (float*)d_out;                   // [4,2048,2048]

    // Workspace layout (208 MiB):
    //   [0, 128M)        x_proj bf16 [8192][8192]
    //   [128M, 192M)     phase 1: xb [8192][2048] bf16 (32M) + winb [8192][2048] bf16 (32M)
    //                    phase 2 (after GEMM1): h bf16 [8192][4096] (64M, aliases xb+winb)
    //   [192M, 208M)     woutb [2048][4096] bf16
    char* wsc = (char*)d_ws;
    __hip_bfloat16* xproj = (__hip_bfloat16*)wsc;
    __hip_bfloat16* xb    = (__hip_bfloat16*)(wsc + (size_t)134217728);
    __hip_bfloat16* winb  = (__hip_bfloat16*)(wsc + (size_t)134217728 + 33554432);
    __hip_bfloat16* hbuf  = (__hip_bfloat16*)(wsc + (size_t)134217728);  // aliases xb/winb
    __hip_bfloat16* woutb = (__hip_bfloat16*)(wsc + (size_t)201326592);

    // 1) fp32 -> bf16 converts
    f32_to_bf16_x4<<<(BT_TOTAL * DM / 4 + 255) / 256, 256, 0, stream>>>(x, xb, BT_TOTAL * DM / 4);
    f32_to_bf16_x4<<<(2 * DI * DM / 4 + 255) / 256, 256, 0, stream>>>(w_in, winb, 2 * DI * DM / 4);
    f32_to_bf16_x4<<<(DM * DI / 4 + 255) / 256, 256, 0, stream>>>(w_out, woutb, DM * DI / 4);

    // 2) GEMM1: x_proj[bt,d] = sum_c x[bt,c] * w_in[d,c]   (M=8192,N=8192,K=2048)
    gemm_bt_kernel<true><<<dim3(2 * DI / 128, BT_TOTAL / 128), 256, 0, stream>>>(
        (const ushort*)xb, (const ushort*)winb, xproj, BT_TOTAL, 2 * DI, DM);

    // 3) conv + silu + gate  (writes hbuf over dead xb/winb — stream-ordered)
    conv_silu_kernel<<<(BT_TOTAL * DI) / 256, 256, 0, stream>>>(xproj, cw, cb, Dv, hbuf);

    // 4) GEMM2: out[bt,c] = sum_d h[bt,d] * w_out[c,d]   (M=8192,N=2048,K=4096)
    gemm_bt_kernel<false><<<dim3(DM / 128, BT_TOTAL / 128), 256, 0, stream>>>(
        (const ushort*)hbuf, (const ushort*)woutb, out, BT_TOTAL, DM, DI);
}

// Round 2
// 740.744 us; speedup vs baseline: 1.1432x; 1.1432x over previous
//
#include <hip/hip_runtime.h>
#include <hip/hip_bf16.h>
#include <stdint.h>

// ---------------------------------------------------------------------------
// Mamba2 block: x@w_in^T -> split(xi,gate) -> depthwise causal conv4 + silu
//               -> *D*silu(gate) -> @w_out^T
// B=4, T=2048, D_MODEL=2048, D_INNER=4096.  All GEMMs in bf16 MFMA, fp32 acc.
//
// R1: XOR-swizzled LDS chunk columns (chunk c of row r lives at col c^(r&7))
//     to kill the 16-way ds_read_b128 bank aliasing (SQ_LDS_BANK_CONFLICT
//     was 1.0e8 = ~38% of GEMM cycles). Swizzle is applied by permuting the
//     GLOBAL source per lane (global_load_lds pins LDS slot = base+lane*16).
// ---------------------------------------------------------------------------

#define BT_TOTAL 8192   // B*T
#define DM 2048
#define DI 4096

typedef __attribute__((ext_vector_type(8))) short short8;   // 8 x bf16 (4 VGPR)
typedef __attribute__((ext_vector_type(4))) float f32x4;    // MFMA C/D

__device__ __forceinline__ void async_ld16(const void* g, void* l) {
    __builtin_amdgcn_global_load_lds(
        (__attribute__((address_space(1))) void*)g,
        (__attribute__((address_space(3))) void*)l,
        16, 0, 0);
}

// gemm_bt: C[M,N] = A[M,K] * B[N,K]^T   (both K-contiguous), bf16 in, fp32 acc.
// 128x128 tile, BK=64, 256 threads = 4 waves in 2x2, each wave 64x64 via
// 4x4 grid of 16x16x32 MFMA tiles.
template<bool OUT_BF16>
__global__ __launch_bounds__(256) void gemm_bt_kernel(
    const ushort* __restrict__ A, const ushort* __restrict__ B,
    void* __restrict__ Cp, int M, int N, int K)
{
    __shared__ ushort As[128 * 64];   // 16 KiB
    __shared__ ushort Bs[128 * 64];   // 16 KiB

    const int tid  = threadIdx.x;
    const int lane = tid & 63;
    const int wave = tid >> 6;
    const int wm   = (wave >> 1) * 64;   // wave row offset inside tile
    const int wn   = (wave & 1) * 64;    // wave col offset inside tile
    const int lr   = lane & 15;
    const int quad = lane >> 4;

    const int bm = blockIdx.y * 128;
    const int bn = blockIdx.x * 128;

    f32x4 acc[4][4];
#pragma unroll
    for (int i = 0; i < 4; ++i)
#pragma unroll
        for (int j = 0; j < 4; ++j)
            acc[i][j] = (f32x4){0.f, 0.f, 0.f, 0.f};

    // Staging: tile = 128 rows x 64 bf16 = 1024 x 16B chunks; 256 thr x 4.
    // LDS slot for linear chunk c is fixed at c*16 (global_load_lds rule).
    // Slot c holds global (row = c>>3, chunk col = (c&7) ^ (row&7)) -> the
    // XOR swizzle lives in the global source address, not the LDS address.
    const ushort* ag[4];
    const ushort* bg[4];
    ushort* al[4];
    ushort* bl[4];
#pragma unroll
    for (int t = 0; t < 4; ++t) {
        const int c  = tid + t * 256;
        const int r  = c >> 3;
        const int co = ((c & 7) ^ (r & 7)) * 8;   // swizzled source column
        ag[t] = A + (size_t)(bm + r) * (size_t)K + co;
        bg[t] = B + (size_t)(bn + r) * (size_t)K + co;
        al[t] = &As[c * 8];
        bl[t] = &Bs[c * 8];
    }

    for (int kk = 0; kk < K; kk += 64) {
        __syncthreads();                 // everyone done reading previous tile
#pragma unroll
        for (int t = 0; t < 4; ++t) {
            async_ld16(ag[t] + kk, al[t]);
            async_ld16(bg[t] + kk, bl[t]);
        }
        __syncthreads();                 // drains vmcnt before barrier

#pragma unroll
        for (int ks = 0; ks < 64; ks += 32) {
            // swizzled read column: chunk = (quad + ks/8) ^ (row&7), row&7==lr&7
            const int ca = ((quad + (ks >> 3)) ^ (lr & 7)) * 8;
            short8 af[4], bfr[4];
#pragma unroll
            for (int mt = 0; mt < 4; ++mt)
                af[mt] = *(const short8*)&As[(wm + mt * 16 + lr) * 64 + ca];
#pragma unroll
            for (int nt = 0; nt < 4; ++nt)
                bfr[nt] = *(const short8*)&Bs[(wn + nt * 16 + lr) * 64 + ca];
#pragma unroll
            for (int mt = 0; mt < 4; ++mt)
#pragma unroll
                for (int nt = 0; nt < 4; ++nt)
                    acc[mt][nt] = __builtin_amdgcn_mfma_f32_16x16x32_bf16(
                        af[mt], bfr[nt], acc[mt][nt], 0, 0, 0);
        }
    }

    // Epilogue. C/D layout (verified m89/m91): col = lane&15, row = quad*4+reg.
    const int row0 = bm + wm + quad * 4;
    const int col0 = bn + wn + lr;
    if (OUT_BF16) {
        __hip_bfloat16* C = (__hip_bfloat16*)Cp;
#pragma unroll
        for (int mt = 0; mt < 4; ++mt)
#pragma unroll
            for (int r = 0; r < 4; ++r) {
                const int gr = row0 + mt * 16 + r;
                __hip_bfloat16* Crow = C + (size_t)gr * (size_t)N + col0;
#pragma unroll
                for (int nt = 0; nt < 4; ++nt)
                    Crow[nt * 16] = __float2bfloat16(acc[mt][nt][r]);
            }
    } else {
        float* C = (float*)Cp;
#pragma unroll
        for (int mt = 0; mt < 4; ++mt)
#pragma unroll
            for (int r = 0; r < 4; ++r) {
                const int gr = row0 + mt * 16 + r;
                float* Crow = C + (size_t)gr * (size_t)N + col0;
#pragma unroll
                for (int nt = 0; nt < 4; ++nt)
                    Crow[nt * 16] = acc[mt][nt][r];
            }
    }
}

// Depthwise causal conv (4 taps) + silu, * D, * silu(gate).
__global__ __launch_bounds__(256) void conv_silu_kernel(
    const __hip_bfloat16* __restrict__ xp,
    const float* __restrict__ cw,   // [4096][4]
    const float* __restrict__ cb,   // [4096]
    const float* __restrict__ Dv,   // [4096]
    __hip_bfloat16* __restrict__ h)
{
    const int idx = blockIdx.x * 256 + threadIdx.x;   // over 8192*4096
    const int d  = idx & (DI - 1);
    const int bt = idx >> 12;
    const int t  = bt & 2047;

    const float gate = __bfloat162float(xp[(size_t)bt * (2 * DI) + DI + d]);

    float a = cb[d];
    const float4 w = *(const float4*)(cw + d * 4);
    const float wk[4] = {w.x, w.y, w.z, w.w};
#pragma unroll
    for (int k = 0; k < 4; ++k) {
        const int tt = t - 3 + k;
        if (tt >= 0)
            a += __bfloat162float(xp[(size_t)(bt - 3 + k) * (2 * DI) + d]) * wk[k];
    }
    const float sc = a / (1.f + __expf(-a));
    const float sg = gate / (1.f + __expf(-gate));
    h[(size_t)bt * DI + d] = __float2bfloat16(sc * Dv[d] * sg);
}

__global__ __launch_bounds__(256) void f32_to_bf16_x4(
    const float* __restrict__ in, __hip_bfloat16* __restrict__ out, int n4)
{
    const int i = blockIdx.x * 256 + threadIdx.x;
    if (i >= n4) return;
    const float4 v = *(const float4*)(in + (size_t)i * 4);
    union { __hip_bfloat16 hh[4]; ushort4 u; } cv;
    cv.hh[0] = __float2bfloat16(v.x);
    cv.hh[1] = __float2bfloat16(v.y);
    cv.hh[2] = __float2bfloat16(v.z);
    cv.hh[3] = __float2bfloat16(v.w);
    *(ushort4*)((ushort*)out + (size_t)i * 4) = cv.u;
}

extern "C" void kernel_launch(void* const* d_in, const int* in_sizes, int n_in,
                              void* d_out, int out_size, void* d_ws, size_t ws_size,
                              hipStream_t stream)
{
    const float* x     = (const float*)d_in[0];   // [4,2048,2048]
    const float* w_in  = (const float*)d_in[1];   // [8192,2048]
    const float* w_out = (const float*)d_in[2];   // [2048,4096]
    const float* cw    = (const float*)d_in[3];   // [4096,1,4]
    const float* cb    = (const float*)d_in[4];   // [4096]
    const float* Dv    = (const float*)d_in[5];   // [4096]
    float* out = (float*)d_out;                   // [4,2048,2048]

    // Workspace layout (208 MiB):
    //   [0, 128M)        x_proj bf16 [8192][8192]
    //   [128M, 192M)     phase 1: xb (32M) + winb (32M); phase 2: h bf16 (64M)
    //   [192M, 208M)     woutb [2048][4096] bf16
    char* wsc = (char*)d_ws;
    __hip_bfloat16* xproj = (__hip_bfloat16*)wsc;
    __hip_bfloat16* xb    = (__hip_bfloat16*)(wsc + (size_t)134217728);
    __hip_bfloat16* winb  = (__hip_bfloat16*)(wsc + (size_t)134217728 + 33554432);
    __hip_bfloat16* hbuf  = (__hip_bfloat16*)(wsc + (size_t)134217728);  // aliases xb/winb
    __hip_bfloat16* woutb = (__hip_bfloat16*)(wsc + (size_t)201326592);

    // 1) fp32 -> bf16 converts
    f32_to_bf16_x4<<<(BT_TOTAL * DM / 4 + 255) / 256, 256, 0, stream>>>(x, xb, BT_TOTAL * DM / 4);
    f32_to_bf16_x4<<<(2 * DI * DM / 4 + 255) / 256, 256, 0, stream>>>(w_in, winb, 2 * DI * DM / 4);
    f32_to_bf16_x4<<<(DM * DI / 4 + 255) / 256, 256, 0, stream>>>(w_out, woutb, DM * DI / 4);

    // 2) GEMM1: x_proj[bt,d] = sum_c x[bt,c] * w_in[d,c]   (M=8192,N=8192,K=2048)
    gemm_bt_kernel<true><<<dim3(2 * DI / 128, BT_TOTAL / 128), 256, 0, stream>>>(
        (const ushort*)xb, (const ushort*)winb, xproj, BT_TOTAL, 2 * DI, DM);

    // 3) conv + silu + gate  (writes hbuf over dead xb/winb — stream-ordered)
    conv_silu_kernel<<<(BT_TOTAL * DI) / 256, 256, 0, stream>>>(xproj, cw, cb, Dv, hbuf);

    // 4) GEMM2: out[bt,c] = sum_d h[bt,d] * w_out[c,d]   (M=8192,N=2048,K=4096)
    gemm_bt_kernel<false><<<dim3(DM / 128, BT_TOTAL / 128), 256, 0, stream>>>(
        (const ushort*)hbuf, (const ushort*)woutb, out, BT_TOTAL, DM, DI);
}

// Round 4
// 719.276 us; speedup vs baseline: 1.1773x; 1.0298x over previous
//
#include <hip/hip_runtime.h>
#include <hip/hip_bf16.h>
#include <stdint.h>
#include <string.h>

// ---------------------------------------------------------------------------
// Mamba2 block: x@w_in^T -> split(xi,gate) -> depthwise causal conv4 + silu
//               -> *D*silu(gate) -> @w_out^T
// B=4, T=2048, D_MODEL=2048, D_INNER=4096.  GEMMs in bf16 MFMA, fp32 acc.
//
// R1: XOR-swizzled LDS (conflicts 1.0e8 -> 0, 847 -> 741 us).
// R2: (a) 32x32x16 MFMA (half the MFMA instrs, 2495 vs 2176 TF pipe rate),
//     (b) saddr-form staging (uniform base + 32-bit lane offset) + hoisted
//         LDS read pointers to cut VALUBusy (was 54% > MfmaUtil 45%),
//     (c) conv kernel vectorized x8 (uint4 bf16 loads/stores).
// R3: fix compile — __hip_bfloat16 has no .data member; bit-cast via union.
// ---------------------------------------------------------------------------

#define BT_TOTAL 8192   // B*T
#define DM 2048
#define DI 4096

typedef __attribute__((ext_vector_type(8)))  short short8;   // 8 x bf16
typedef __attribute__((ext_vector_type(16))) float f32x16;   // 32x32 C/D

__device__ __forceinline__ void async_ld16(const void* g, void* l) {
    __builtin_amdgcn_global_load_lds(
        (__attribute__((address_space(1))) void*)g,
        (__attribute__((address_space(3))) void*)l,
        16, 0, 0);
}

__device__ __forceinline__ float bf2f(ushort u) {
    union { uint i; float f; } v; v.i = ((uint)u) << 16; return v.f;
}

__device__ __forceinline__ ushort f2bf_bits(float f) {
    union { __hip_bfloat16 b; ushort u; } v;
    v.b = __float2bfloat16(f);
    return v.u;
}

// gemm_bt: C[M,N] = A[M,K] * B[N,K]^T  (both K-contiguous), bf16 in, fp32 acc.
// 128x128 tile, BK=64, 4 waves in 2x2; each wave 64x64 via 2x2 of 32x32x16.
template<bool OUT_BF16>
__global__ __launch_bounds__(256) void gemm_bt_kernel(
    const ushort* __restrict__ A, const ushort* __restrict__ B,
    void* __restrict__ Cp, int M, int N, int K)
{
    __shared__ ushort As[128 * 64];   // 16 KiB
    __shared__ ushort Bs[128 * 64];   // 16 KiB

    const int tid  = threadIdx.x;
    const int lane = tid & 63;
    const int wave = tid >> 6;
    const int wm   = (wave >> 1) * 64;
    const int wn   = (wave & 1) * 64;
    const int l31  = lane & 31;
    const int half = lane >> 5;        // 0/1

    const int bm = blockIdx.y * 128;
    const int bn = blockIdx.x * 128;

    f32x16 acc[2][2];
#pragma unroll
    for (int i = 0; i < 2; ++i)
#pragma unroll
        for (int j = 0; j < 2; ++j)
#pragma unroll
            for (int r = 0; r < 16; ++r)
                acc[i][j][r] = 0.f;

    // Staging: tile = 128 rows x 64 bf16 = 1024 x 16B chunks; 256 thr x 4.
    // LDS slot for linear chunk c is fixed (global_load_lds rule); slot c
    // holds global (row = c>>3, chunk = (c&7) ^ (row&7)) — XOR swizzle in
    // the GLOBAL source address.  Offsets are 32-bit ints so the base
    // (A + kk, wave-uniform) can go to SGPRs (saddr form, no 64-bit VALU).
    int aoff[4], boff[4];
    ushort* al[4];
    ushort* bl[4];
#pragma unroll
    for (int t = 0; t < 4; ++t) {
        const int c  = tid + t * 256;
        const int r  = c >> 3;
        const int co = ((c & 7) ^ (r & 7)) * 8;
        aoff[t] = (bm + r) * K + co;
        boff[t] = (bn + r) * K + co;
        al[t] = &As[c * 8];
        bl[t] = &Bs[c * 8];
    }

    // Loop-invariant LDS fragment pointers.
    // A frag (32x32x16): row = lane&31, k = (lane>>5)*8 + j.  Logical 16B
    // chunk q = s*2 + half for k-step s; physical chunk = q ^ (row&7).
    const ushort* aP[8];   // [s][tm] flattened: s*2+tm
    const ushort* bP[8];
#pragma unroll
    for (int s = 0; s < 4; ++s)
#pragma unroll
        for (int tt = 0; tt < 2; ++tt) {
            const int rowA = wm + tt * 32 + l31;
            const int rowB = wn + tt * 32 + l31;
            const int q = s * 2 + half;
            aP[s * 2 + tt] = &As[rowA * 64 + (q ^ (rowA & 7)) * 8];
            bP[s * 2 + tt] = &Bs[rowB * 64 + (q ^ (rowB & 7)) * 8];
        }

    for (int kk = 0; kk < K; kk += 64) {
        const ushort* Ak = A + kk;     // wave-uniform base -> SGPR
        const ushort* Bk = B + kk;
        __syncthreads();               // everyone done reading previous tile
#pragma unroll
        for (int t = 0; t < 4; ++t) {
            async_ld16(Ak + aoff[t], al[t]);
            async_ld16(Bk + boff[t], bl[t]);
        }
        __syncthreads();               // drains vmcnt before barrier

#pragma unroll
        for (int s = 0; s < 4; ++s) {
            short8 af[2], bf[2];
#pragma unroll
            for (int tt = 0; tt < 2; ++tt) {
                af[tt] = *(const short8*)aP[s * 2 + tt];
                bf[tt] = *(const short8*)bP[s * 2 + tt];
            }
#pragma unroll
            for (int tm = 0; tm < 2; ++tm)
#pragma unroll
                for (int tn = 0; tn < 2; ++tn)
                    acc[tm][tn] = __builtin_amdgcn_mfma_f32_32x32x16_bf16(
                        af[tm], bf[tn], acc[tm][tn], 0, 0, 0);
        }
    }

    // Epilogue. 32x32 C/D layout (verified m74/m101):
    //   col = lane&31, row = (reg&3) + 8*(reg>>2) + 4*(lane>>5)
    const int col0  = bn + wn + l31;
    const int rbase = bm + wm + 4 * half;
    if (OUT_BF16) {
        __hip_bfloat16* C = (__hip_bfloat16*)Cp;
#pragma unroll
        for (int tm = 0; tm < 2; ++tm)
#pragma unroll
            for (int tn = 0; tn < 2; ++tn)
#pragma unroll
                for (int r = 0; r < 16; ++r) {
                    const int row = rbase + tm * 32 + (r & 3) + 8 * (r >> 2);
                    C[(size_t)row * (size_t)N + col0 + tn * 32] =
                        __float2bfloat16(acc[tm][tn][r]);
                }
    } else {
        float* C = (float*)Cp;
#pragma unroll
        for (int tm = 0; tm < 2; ++tm)
#pragma unroll
            for (int tn = 0; tn < 2; ++tn)
#pragma unroll
                for (int r = 0; r < 16; ++r) {
                    const int row = rbase + tm * 32 + (r & 3) + 8 * (r >> 2);
                    C[(size_t)row * (size_t)N + col0 + tn * 32] = acc[tm][tn][r];
                }
    }
}

// Depthwise causal conv (4 taps) + silu, * D, * silu(gate).  8 d's / thread.
__global__ __launch_bounds__(256) void conv_silu_kernel(
    const ushort* __restrict__ xp,   // bf16 [8192][8192]
    const float* __restrict__ cw,    // [4096][4]
    const float* __restrict__ cb,    // [4096]
    const float* __restrict__ Dv,    // [4096]
    ushort* __restrict__ h)          // bf16 [8192][4096]
{
    const int v  = blockIdx.x * 256 + threadIdx.x;   // over 8192*512
    const int d8 = (v & 511) * 8;
    const int bt = v >> 9;
    const int t  = bt & 2047;

    const uint4 gv = *(const uint4*)(xp + (size_t)bt * (2 * DI) + DI + d8);
    uint4 tap[4];
#pragma unroll
    for (int k = 0; k < 4; ++k) {
        const int tt = t - 3 + k;
        if (tt >= 0)
            tap[k] = *(const uint4*)(xp + (size_t)(bt - 3 + k) * (2 * DI) + d8);
        else
            tap[k] = (uint4){0u, 0u, 0u, 0u};
    }

    const float4* cwv = (const float4*)(cw + (size_t)d8 * 4);   // 8 x float4
    const float4  cb0 = *(const float4*)(cb + d8);
    const float4  cb1 = *(const float4*)(cb + d8 + 4);
    const float4  dv0 = *(const float4*)(Dv + d8);
    const float4  dv1 = *(const float4*)(Dv + d8 + 4);
    const float cbs[8] = {cb0.x, cb0.y, cb0.z, cb0.w, cb1.x, cb1.y, cb1.z, cb1.w};
    const float dvs[8] = {dv0.x, dv0.y, dv0.z, dv0.w, dv1.x, dv1.y, dv1.z, dv1.w};

    ushort res[8];
#pragma unroll
    for (int j = 0; j < 8; ++j) {
        float a = cbs[j];
        const float4 w = cwv[j];
        const float wk[4] = {w.x, w.y, w.z, w.w};
#pragma unroll
        for (int k = 0; k < 4; ++k) {
            const uint u = ((const uint*)&tap[k])[j >> 1];
            const ushort us = (j & 1) ? (ushort)(u >> 16) : (ushort)(u & 0xffff);
            a += bf2f(us) * wk[k];
        }
        const uint gu = ((const uint*)&gv)[j >> 1];
        const ushort gs = (j & 1) ? (ushort)(gu >> 16) : (ushort)(gu & 0xffff);
        const float g = bf2f(gs);
        const float sc = a / (1.f + __expf(-a));
        const float sg = g / (1.f + __expf(-g));
        res[j] = f2bf_bits(sc * dvs[j] * sg);
    }
    *(uint4*)(h + (size_t)bt * DI + d8) = *(const uint4*)res;
}

__global__ __launch_bounds__(256) void f32_to_bf16_x4(
    const float* __restrict__ in, __hip_bfloat16* __restrict__ out, int n4)
{
    const int i = blockIdx.x * 256 + threadIdx.x;
    if (i >= n4) return;
    const float4 v = *(const float4*)(in + (size_t)i * 4);
    union { __hip_bfloat16 hh[4]; ushort4 u; } cv;
    cv.hh[0] = __float2bfloat16(v.x);
    cv.hh[1] = __float2bfloat16(v.y);
    cv.hh[2] = __float2bfloat16(v.z);
    cv.hh[3] = __float2bfloat16(v.w);
    *(ushort4*)((ushort*)out + (size_t)i * 4) = cv.u;
}

extern "C" void kernel_launch(void* const* d_in, const int* in_sizes, int n_in,
                              void* d_out, int out_size, void* d_ws, size_t ws_size,
                              hipStream_t stream)
{
    const float* x     = (const float*)d_in[0];   // [4,2048,2048]
    const float* w_in  = (const float*)d_in[1];   // [8192,2048]
    const float* w_out = (const float*)d_in[2];   // [2048,4096]
    const float* cw    = (const float*)d_in[3];   // [4096,1,4]
    const float* cb    = (const float*)d_in[4];   // [4096]
    const float* Dv    = (const float*)d_in[5];   // [4096]
    float* out = (float*)d_out;                   // [4,2048,2048]

    // Workspace layout (208 MiB):
    //   [0, 128M)        x_proj bf16 [8192][8192]
    //   [128M, 192M)     phase 1: xb (32M) + winb (32M); phase 2: h bf16 (64M)
    //   [192M, 208M)     woutb [2048][4096] bf16
    char* wsc = (char*)d_ws;
    __hip_bfloat16* xproj = (__hip_bfloat16*)wsc;
    __hip_bfloat16* xb    = (__hip_bfloat16*)(wsc + (size_t)134217728);
    __hip_bfloat16* winb  = (__hip_bfloat16*)(wsc + (size_t)134217728 + 33554432);
    __hip_bfloat16* hbuf  = (__hip_bfloat16*)(wsc + (size_t)134217728);  // aliases xb/winb
    __hip_bfloat16* woutb = (__hip_bfloat16*)(wsc + (size_t)201326592);

    // 1) fp32 -> bf16 converts
    f32_to_bf16_x4<<<(BT_TOTAL * DM / 4 + 255) / 256, 256, 0, stream>>>(x, xb, BT_TOTAL * DM / 4);
    f32_to_bf16_x4<<<(2 * DI * DM / 4 + 255) / 256, 256, 0, stream>>>(w_in, winb, 2 * DI * DM / 4);
    f32_to_bf16_x4<<<(DM * DI / 4 + 255) / 256, 256, 0, stream>>>(w_out, woutb, DM * DI / 4);

    // 2) GEMM1: x_proj[bt,d] = sum_c x[bt,c] * w_in[d,c]   (M=8192,N=8192,K=2048)
    gemm_bt_kernel<true><<<dim3(2 * DI / 128, BT_TOTAL / 128), 256, 0, stream>>>(
        (const ushort*)xb, (const ushort*)winb, xproj, BT_TOTAL, 2 * DI, DM);

    // 3) conv + silu + gate  (writes hbuf over dead xb/winb — stream-ordered)
    conv_silu_kernel<<<(BT_TOTAL * DI / 8) / 256, 256, 0, stream>>>(
        (const ushort*)xproj, cw, cb, Dv, (ushort*)hbuf);

    // 4) GEMM2: out[bt,c] = sum_d h[bt,d] * w_out[c,d]   (M=8192,N=2048,K=4096)
    gemm_bt_kernel<false><<<dim3(DM / 128, BT_TOTAL / 128), 256, 0, stream>>>(
        (const ushort*)hbuf, (const ushort*)woutb, out, BT_TOTAL, DM, DI);
}

// Round 5
// 716.182 us; speedup vs baseline: 1.1824x; 1.0043x over previous
//
#include <hip/hip_runtime.h>
#include <hip/hip_bf16.h>
#include <stdint.h>
#include <string.h>

// ---------------------------------------------------------------------------
// Mamba2 block: x@w_in^T -> split(xi,gate) -> depthwise causal conv4 + silu
//               -> *D*silu(gate) -> @w_out^T
// B=4, T=2048, D_MODEL=2048, D_INNER=4096.  GEMMs in bf16 MFMA, fp32 acc.
//
// R1: XOR-swizzle f(r)=r&7 (conflicts 1.0e8 -> 0 w/ 16x16 frags).
// R2: 32x32x16 MFMA + saddr staging + hoisted LDS ptrs (VALU 54->14%), BUT
//     f(r)=r&7 conflicts with 32x32 frag reads (stride-8 lanes share banks):
//     3.35e7 conflicts = +4 cyc per ds_read_b128.
// R5: swizzle strengthened to f(r) = (r ^ (r>>3)) & 7 — every aligned 8-lane
//     group is a full chunk permutation AND stride-8/16/24 lanes diverge.
// ---------------------------------------------------------------------------

#define BT_TOTAL 8192   // B*T
#define DM 2048
#define DI 4096

typedef __attribute__((ext_vector_type(8)))  short short8;   // 8 x bf16
typedef __attribute__((ext_vector_type(16))) float f32x16;   // 32x32 C/D

__device__ __forceinline__ void async_ld16(const void* g, void* l) {
    __builtin_amdgcn_global_load_lds(
        (__attribute__((address_space(1))) void*)g,
        (__attribute__((address_space(3))) void*)l,
        16, 0, 0);
}

__device__ __forceinline__ float bf2f(ushort u) {
    union { uint i; float f; } v; v.i = ((uint)u) << 16; return v.f;
}

__device__ __forceinline__ ushort f2bf_bits(float f) {
    union { __hip_bfloat16 b; ushort u; } v;
    v.b = __float2bfloat16(f);
    return v.u;
}

// gemm_bt: C[M,N] = A[M,K] * B[N,K]^T  (both K-contiguous), bf16 in, fp32 acc.
// 128x128 tile, BK=64, 4 waves in 2x2; each wave 64x64 via 2x2 of 32x32x16.
template<bool OUT_BF16>
__global__ __launch_bounds__(256) void gemm_bt_kernel(
    const ushort* __restrict__ A, const ushort* __restrict__ B,
    void* __restrict__ Cp, int M, int N, int K)
{
    __shared__ ushort As[128 * 64];   // 16 KiB
    __shared__ ushort Bs[128 * 64];   // 16 KiB

    const int tid  = threadIdx.x;
    const int lane = tid & 63;
    const int wave = tid >> 6;
    const int wm   = (wave >> 1) * 64;
    const int wn   = (wave & 1) * 64;
    const int l31  = lane & 31;
    const int half = lane >> 5;        // 0/1

    const int bm = blockIdx.y * 128;
    const int bn = blockIdx.x * 128;

    f32x16 acc[2][2];
#pragma unroll
    for (int i = 0; i < 2; ++i)
#pragma unroll
        for (int j = 0; j < 2; ++j)
#pragma unroll
            for (int r = 0; r < 16; ++r)
                acc[i][j][r] = 0.f;

    // Staging: tile = 128 rows x 64 bf16 = 1024 x 16B chunks; 256 thr x 4.
    // LDS slot for linear chunk c is fixed (global_load_lds rule); slot
    // (row r, pos j) holds global chunk j ^ f(r), f(r) = (r ^ (r>>3)) & 7.
    // Swizzle is in the GLOBAL source address.  32-bit offsets keep the
    // wave-uniform base (A + kk) in SGPRs (saddr form).
    int aoff[4], boff[4];
    ushort* al[4];
    ushort* bl[4];
#pragma unroll
    for (int t = 0; t < 4; ++t) {
        const int c  = tid + t * 256;
        const int r  = c >> 3;
        const int fr = (r ^ (r >> 3)) & 7;
        const int co = ((c & 7) ^ fr) * 8;
        aoff[t] = (bm + r) * K + co;
        boff[t] = (bn + r) * K + co;
        al[t] = &As[c * 8];
        bl[t] = &Bs[c * 8];
    }

    // Loop-invariant LDS fragment pointers.
    // A frag (32x32x16): row = lane&31, k = (lane>>5)*8 + j  -> logical 16B
    // chunk q = s*2 + half; physical chunk = q ^ f(row).
    const ushort* aP[8];   // [s][tt] flattened: s*2+tt
    const ushort* bP[8];
#pragma unroll
    for (int s = 0; s < 4; ++s)
#pragma unroll
        for (int tt = 0; tt < 2; ++tt) {
            const int rowA = wm + tt * 32 + l31;
            const int rowB = wn + tt * 32 + l31;
            const int fA = (rowA ^ (rowA >> 3)) & 7;
            const int fB = (rowB ^ (rowB >> 3)) & 7;
            const int q = s * 2 + half;
            aP[s * 2 + tt] = &As[rowA * 64 + (q ^ fA) * 8];
            bP[s * 2 + tt] = &Bs[rowB * 64 + (q ^ fB) * 8];
        }

    for (int kk = 0; kk < K; kk += 64) {
        const ushort* Ak = A + kk;     // wave-uniform base -> SGPR
        const ushort* Bk = B + kk;
        __syncthreads();               // everyone done reading previous tile
#pragma unroll
        for (int t = 0; t < 4; ++t) {
            async_ld16(Ak + aoff[t], al[t]);
            async_ld16(Bk + boff[t], bl[t]);
        }
        __syncthreads();               // drains vmcnt before barrier

#pragma unroll
        for (int s = 0; s < 4; ++s) {
            short8 af[2], bf[2];
#pragma unroll
            for (int tt = 0; tt < 2; ++tt) {
                af[tt] = *(const short8*)aP[s * 2 + tt];
                bf[tt] = *(const short8*)bP[s * 2 + tt];
            }
#pragma unroll
            for (int tm = 0; tm < 2; ++tm)
#pragma unroll
                for (int tn = 0; tn < 2; ++tn)
                    acc[tm][tn] = __builtin_amdgcn_mfma_f32_32x32x16_bf16(
                        af[tm], bf[tn], acc[tm][tn], 0, 0, 0);
        }
    }

    // Epilogue. 32x32 C/D layout (verified m74/m101):
    //   col = lane&31, row = (reg&3) + 8*(reg>>2) + 4*(lane>>5)
    const int col0  = bn + wn + l31;
    const int rbase = bm + wm + 4 * half;
    if (OUT_BF16) {
        __hip_bfloat16* C = (__hip_bfloat16*)Cp;
#pragma unroll
        for (int tm = 0; tm < 2; ++tm)
#pragma unroll
            for (int tn = 0; tn < 2; ++tn)
#pragma unroll
                for (int r = 0; r < 16; ++r) {
                    const int row = rbase + tm * 32 + (r & 3) + 8 * (r >> 2);
                    C[(size_t)row * (size_t)N + col0 + tn * 32] =
                        __float2bfloat16(acc[tm][tn][r]);
                }
    } else {
        float* C = (float*)Cp;
#pragma unroll
        for (int tm = 0; tm < 2; ++tm)
#pragma unroll
            for (int tn = 0; tn < 2; ++tn)
#pragma unroll
                for (int r = 0; r < 16; ++r) {
                    const int row = rbase + tm * 32 + (r & 3) + 8 * (r >> 2);
                    C[(size_t)row * (size_t)N + col0 + tn * 32] = acc[tm][tn][r];
                }
    }
}

// Depthwise causal conv (4 taps) + silu, * D, * silu(gate).  8 d's / thread.
__global__ __launch_bounds__(256) void conv_silu_kernel(
    const ushort* __restrict__ xp,   // bf16 [8192][8192]
    const float* __restrict__ cw,    // [4096][4]
    const float* __restrict__ cb,    // [4096]
    const float* __restrict__ Dv,    // [4096]
    ushort* __restrict__ h)          // bf16 [8192][4096]
{
    const int v  = blockIdx.x * 256 + threadIdx.x;   // over 8192*512
    const int d8 = (v & 511) * 8;
    const int bt = v >> 9;
    const int t  = bt & 2047;

    const uint4 gv = *(const uint4*)(xp + (size_t)bt * (2 * DI) + DI + d8);
    uint4 tap[4];
#pragma unroll
    for (int k = 0; k < 4; ++k) {
        const int tt = t - 3 + k;
        if (tt >= 0)
            tap[k] = *(const uint4*)(xp + (size_t)(bt - 3 + k) * (2 * DI) + d8);
        else
            tap[k] = (uint4){0u, 0u, 0u, 0u};
    }

    const float4* cwv = (const float4*)(cw + (size_t)d8 * 4);   // 8 x float4
    const float4  cb0 = *(const float4*)(cb + d8);
    const float4  cb1 = *(const float4*)(cb + d8 + 4);
    const float4  dv0 = *(const float4*)(Dv + d8);
    const float4  dv1 = *(const float4*)(Dv + d8 + 4);
    const float cbs[8] = {cb0.x, cb0.y, cb0.z, cb0.w, cb1.x, cb1.y, cb1.z, cb1.w};
    const float dvs[8] = {dv0.x, dv0.y, dv0.z, dv0.w, dv1.x, dv1.y, dv1.z, dv1.w};

    ushort res[8];
#pragma unroll
    for (int j = 0; j < 8; ++j) {
        float a = cbs[j];
        const float4 w = cwv[j];
        const float wk[4] = {w.x, w.y, w.z, w.w};
#pragma unroll
        for (int k = 0; k < 4; ++k) {
            const uint u = ((const uint*)&tap[k])[j >> 1];
            const ushort us = (j & 1) ? (ushort)(u >> 16) : (ushort)(u & 0xffff);
            a += bf2f(us) * wk[k];
        }
        const uint gu = ((const uint*)&gv)[j >> 1];
        const ushort gs = (j & 1) ? (ushort)(gu >> 16) : (ushort)(gu & 0xffff);
        const float g = bf2f(gs);
        const float sc = a / (1.f + __expf(-a));
        const float sg = g / (1.f + __expf(-g));
        res[j] = f2bf_bits(sc * dvs[j] * sg);
    }
    *(uint4*)(h + (size_t)bt * DI + d8) = *(const uint4*)res;
}

__global__ __launch_bounds__(256) void f32_to_bf16_x4(
    const float* __restrict__ in, __hip_bfloat16* __restrict__ out, int n4)
{
    const int i = blockIdx.x * 256 + threadIdx.x;
    if (i >= n4) return;
    const float4 v = *(const float4*)(in + (size_t)i * 4);
    union { __hip_bfloat16 hh[4]; ushort4 u; } cv;
    cv.hh[0] = __float2bfloat16(v.x);
    cv.hh[1] = __float2bfloat16(v.y);
    cv.hh[2] = __float2bfloat16(v.z);
    cv.hh[3] = __float2bfloat16(v.w);
    *(ushort4*)((ushort*)out + (size_t)i * 4) = cv.u;
}

extern "C" void kernel_launch(void* const* d_in, const int* in_sizes, int n_in,
                              void* d_out, int out_size, void* d_ws, size_t ws_size,
                              hipStream_t stream)
{
    const float* x     = (const float*)d_in[0];   // [4,2048,2048]
    const float* w_in  = (const float*)d_in[1];   // [8192,2048]
    const float* w_out = (const float*)d_in[2];   // [2048,4096]
    const float* cw    = (const float*)d_in[3];   // [4096,1,4]
    const float* cb    = (const float*)d_in[4];   // [4096]
    const float* Dv    = (const float*)d_in[5];   // [4096]
    float* out = (float*)d_out;                   // [4,2048,2048]

    // Workspace layout (208 MiB):
    //   [0, 128M)        x_proj bf16 [8192][8192]
    //   [128M, 192M)     phase 1: xb (32M) + winb (32M); phase 2: h bf16 (64M)
    //   [192M, 208M)     woutb [2048][4096] bf16
    char* wsc = (char*)d_ws;
    __hip_bfloat16* xproj = (__hip_bfloat16*)wsc;
    __hip_bfloat16* xb    = (__hip_bfloat16*)(wsc + (size_t)134217728);
    __hip_bfloat16* winb  = (__hip_bfloat16*)(wsc + (size_t)134217728 + 33554432);
    __hip_bfloat16* hbuf  = (__hip_bfloat16*)(wsc + (size_t)134217728);  // aliases xb/winb
    __hip_bfloat16* woutb = (__hip_bfloat16*)(wsc + (size_t)201326592);

    // 1) fp32 -> bf16 converts
    f32_to_bf16_x4<<<(BT_TOTAL * DM / 4 + 255) / 256, 256, 0, stream>>>(x, xb, BT_TOTAL * DM / 4);
    f32_to_bf16_x4<<<(2 * DI * DM / 4 + 255) / 256, 256, 0, stream>>>(w_in, winb, 2 * DI * DM / 4);
    f32_to_bf16_x4<<<(DM * DI / 4 + 255) / 256, 256, 0, stream>>>(w_out, woutb, DM * DI / 4);

    // 2) GEMM1: x_proj[bt,d] = sum_c x[bt,c] * w_in[d,c]   (M=8192,N=8192,K=2048)
    gemm_bt_kernel<true><<<dim3(2 * DI / 128, BT_TOTAL / 128), 256, 0, stream>>>(
        (const ushort*)xb, (const ushort*)winb, xproj, BT_TOTAL, 2 * DI, DM);

    // 3) conv + silu + gate  (writes hbuf over dead xb/winb — stream-ordered)
    conv_silu_kernel<<<(BT_TOTAL * DI / 8) / 256, 256, 0, stream>>>(
        (const ushort*)xproj, cw, cb, Dv, (ushort*)hbuf);

    // 4) GEMM2: out[bt,c] = sum_d h[bt,d] * w_out[c,d]   (M=8192,N=2048,K=4096)
    gemm_bt_kernel<false><<<dim3(DM / 128, BT_TOTAL / 128), 256, 0, stream>>>(
        (const ushort*)hbuf, (const ushort*)woutb, out, BT_TOTAL, DM, DI);
}